// Round 8
// baseline (280.860 us; speedup 1.0000x reference)
//
#include <hip/hip_runtime.h>
#include <cstdint>
#include <cstddef>

// ---------------------------------------------------------------------------
// MSA: out = proj(softmax(Q K^T * scale) V) for B=4, N=2048, C=1024, H=16, HD=64
// bf16/f16 MFMA pipeline:
//   1. prep (ONE dispatch): x -> bf16; transpose-convert w_qkv, w_proj.
//   2. GEMM qkv: 256x128 tile, 4 waves x (128x64 out), BK=32, triple-buffered
//      LDS (2 blocks/CU), one raw barrier/K-tile, counted vmcnt.
//      XCD/L2-aware block remap.
//   3. attention: 128 q/block, 4 waves x 32 q-rows, BKV=64, S^T=K·Q^T,
//      no-max softmax, p=exp2(s).
//      R8: attn is ISSUE-SUM bound (R7: MfmaUtil 57 + VALUBusy 43 = 100%).
//      PV moved to K=32 f16 MFMA (40 K=16 -> 20 K=32 instrs, -220 cyc/tile):
//      P A-frags (k=quad*8+j) built from S^T C-layout (kv=quad*4+r) by the
//      R4-verified quad-exchange (8 ds_bpermute + 4 cndmask per frag, two
//      constant addresses), now placed in R7's overlap windows: exchange(A)
//      under QK^T(B), exchange(B) under PV(A). Denominator via ones-B K=32
//      MFMA. V reads are b128 (half per half-tile).
//      K+V LDS double-buffered, 1 barrier/tile, 4 blocks/CU, bijective XCD
//      swizzle (FETCH 142->28 MB measured).
//   4. GEMM proj: same kernel, 128x128 tile -> fp32 d_out
// ---------------------------------------------------------------------------

typedef __attribute__((ext_vector_type(8))) short short8;   // 8 x bf16 (4 VGPRs)
typedef __attribute__((ext_vector_type(4))) float f32x4;    // MFMA C/D
typedef _Float16 half4 __attribute__((ext_vector_type(4))); // 16x16x16 A/B frag
typedef _Float16 half8 __attribute__((ext_vector_type(8))); // 16x16x32 A/B frag

#if __has_builtin(__builtin_amdgcn_exp2f)
#define EXP2F(x) __builtin_amdgcn_exp2f(x)
#else
#define EXP2F(x) __expf((x) * 0.69314718056f)
#endif

__device__ __forceinline__ short f2bf(float x) {            // RNE float->bf16 bits
  unsigned u = __builtin_bit_cast(unsigned, x);
  u += 0x7fffu + ((u >> 16) & 1u);
  return (short)(u >> 16);
}

__device__ __forceinline__ unsigned pkh(float a, float b) { // pack 2xf32 -> f16x2
  auto h = __builtin_amdgcn_cvt_pkrtz(a, b);                // __fp16 ext_vector(2)
  return __builtin_bit_cast(unsigned, h);
}

__device__ __forceinline__ void async16(const void* g, void* l) {
  // 16B per lane, LDS dest = wave-uniform base + lane*16
  __builtin_amdgcn_global_load_lds(
      (const __attribute__((address_space(1))) unsigned*)g,
      (__attribute__((address_space(3))) unsigned*)l, 16, 0, 0);
}

__device__ __forceinline__ void barrier_raw() {
  __asm__ volatile("" ::: "memory");
  __builtin_amdgcn_s_barrier();
  __asm__ volatile("" ::: "memory");
}

// ------------------------------- prep --------------------------------------
// One dispatch: blocks [0,4096) convert x; [4096,7168) transpose w_qkv;
// [7168,8192) transpose w_proj. Branch is block-uniform; barriers legal.

__global__ __launch_bounds__(256) void prep_kernel(
    const float* __restrict__ x, const float* __restrict__ w_qkv,
    const float* __restrict__ w_proj, short* __restrict__ xs,
    short* __restrict__ wqkvT, short* __restrict__ wprojT) {
  __shared__ float tile[32][33];
  const int bid = blockIdx.x, tid = threadIdx.x;
  if (bid < 4096) {                                // x -> bf16, 8 elems/thread
    int i = bid * 256 + tid;
    const float4* p = (const float4*)x + (size_t)i * 2;
    float4 a = p[0], b = p[1];
    short8 r;
    r[0] = f2bf(a.x); r[1] = f2bf(a.y); r[2] = f2bf(a.z); r[3] = f2bf(a.w);
    r[4] = f2bf(b.x); r[5] = f2bf(b.y); r[6] = f2bf(b.z); r[7] = f2bf(b.w);
    *((short8*)xs + i) = r;
    return;
  }
  const float* in;
  short* out;
  int N, bx, by;
  if (bid < 4096 + 3072) {
    int b = bid - 4096;
    in = w_qkv; out = wqkvT; N = 3072; bx = b % 96; by = b / 96;
  } else {
    int b = bid - 7168;
    in = w_proj; out = wprojT; N = 1024; bx = b & 31; by = b >> 5;
  }
  const int K = 1024;
  int n0 = bx * 32, k0 = by * 32;
  int tx = tid & 31, ty = tid >> 5;                // (32,8)
  for (int r = ty; r < 32; r += 8)
    tile[r][tx] = in[(size_t)(k0 + r) * N + n0 + tx];
  __syncthreads();
  for (int r = ty; r < 32; r += 8)
    out[(size_t)(n0 + r) * K + k0 + tx] = f2bf(tile[tx][r]);
}

// ------------------------------- GEMM --------------------------------------
// C[M,Nn] = A[M,1024] * Bt[Nn,1024]^T ; BM x BN block tile, BK=32, 4 waves
// as 2Mx2N, each wave (BM/2)x(BN/2) out = (BM/32)x(BN/32) 16x16x32 MFMA/tile.
// LDS: one [BM+BN][32]-short tile per buffer, chunk-of-4 (16B) XOR swizzle
// applied at stage-source AND frag-read -> conflict-free b128 reads.
// TRIPLE buffered: while computing tile t, stage t+2; end-of-tile wait
// vmcnt(L) keeps t+2's L loads in flight. ONE raw s_barrier per K-tile.
// Block remap: XCD c (id%8) owns m-panels [c*MC,(c+1)*MC); n in chunks of 8.
// MODE 0: QKV epilogue (bias, scale Q by SCALE*log2e, scatter q/k bf16, vT f16)
// MODE 1: proj epilogue (bias, fp32 out)

template <int BM, int BN, int MODE>
__global__ __launch_bounds__(256, 2) void gemm_kernel(
    const short* __restrict__ A, const short* __restrict__ Bt,
    const float* __restrict__ bias, int Nn,
    short* __restrict__ qb, short* __restrict__ kb, short* __restrict__ vtb,
    float* __restrict__ outp) {
  constexpr int K = 1024;
  constexpr int NT = K / 32;                       // 32 K-tiles
  constexpr int MR = BM / 32, NR = BN / 32;        // frags per wave
  constexpr int L = (BM + BN) / 64;                // async16 per thread per tile
  __shared__ __align__(16) short Ts[3][(BM + BN) * 32];
  const int tid = threadIdx.x, wave = tid >> 6, lane = tid & 63;
  const int quad = lane >> 4, l16 = lane & 15;

  // XCD/L2-aware remap: id -> (c = id%8, j = id/8); XCD c owns MC m-panels;
  // within, n in chunks of 8 (requires gridDim.x*gridDim.y % 8 == 0).
  const unsigned bid = blockIdx.x + gridDim.x * blockIdx.y;
  const unsigned c = bid & 7u, j = bid >> 3;
  const unsigned MC = gridDim.y >> 3;              // m-panels per XCD
  const unsigned chunk = MC * 8u;                  // blocks per n-chunk per XCD
  const unsigned nc = j / chunk, rem = j - nc * chunk;
  const unsigned m_idx = c * MC + (rem >> 3);
  const unsigned n_idx = nc * 8u + (rem & 7u);
  const int m0 = (int)m_idx * BM, n0 = (int)n_idx * BN;

  const int wrow = (wave >> 1) * (BM / 2), wcol = (wave & 1) * (BN / 2);

  // staging: row = i*64 + (tid>>2), 16B chunk = tid&3, src chunk XOR (row&3)
  const int srow = tid >> 2;
  const int sch8 = (((tid & 3) ^ (srow & 3)) * 8);          // shorts
  const short* Ag = A + (size_t)(m0 + srow) * K + sch8;
  const short* Bg = Bt + (size_t)(n0 + srow) * K + sch8;
  const int fq8 = ((quad ^ (l16 & 3)) * 8);                 // frag chunk (shorts)

  f32x4 acc[MR][NR] = {};

  auto stage = [&](int b, int kt) {
    char* dst = (char*)Ts[b] + tid * 16;
#pragma unroll
    for (int i = 0; i < BM / 64; ++i)
      async16(Ag + (size_t)(i * 64) * K + kt * 32, dst + i * 4096);
#pragma unroll
    for (int i = 0; i < BN / 64; ++i)
      async16(Bg + (size_t)(i * 64) * K + kt * 32, dst + (BM / 64 + i) * 4096);
  };

  // prologue: stage tiles 0,1 into bufs 0,1; wait tile 0 (keep 1 in flight)
  stage(0, 0);
  stage(1, 1);
  if constexpr (L == 6) asm volatile("s_waitcnt vmcnt(6)" ::: "memory");
  else                  asm volatile("s_waitcnt vmcnt(4)" ::: "memory");
  barrier_raw();

  int cb = 0, sb = 2;
  for (int t = 0; t < NT; ++t) {
    if (t + 2 < NT) stage(sb, t + 2);

    const short* Tb = Ts[cb];
    short8 af[MR], bf[NR];
#pragma unroll
    for (int mf = 0; mf < MR; ++mf)
      af[mf] = *(const short8*)&Tb[(wrow + mf * 16 + l16) * 32 + fq8];
#pragma unroll
    for (int nf = 0; nf < NR; ++nf)
      bf[nf] = *(const short8*)&Tb[(BM + wcol + nf * 16 + l16) * 32 + fq8];

    __builtin_amdgcn_s_setprio(1);
#pragma unroll
    for (int mf = 0; mf < MR; ++mf)
#pragma unroll
      for (int nf = 0; nf < NR; ++nf)
        acc[mf][nf] = __builtin_amdgcn_mfma_f32_16x16x32_bf16(
            af[mf], bf[nf], acc[mf][nf], 0, 0, 0);
    __builtin_amdgcn_s_setprio(0);

    // counted wait: keep t+2's L loads in flight; t+1's (a tile old) retired.
    if (t + 2 < NT) {
      if constexpr (L == 6) asm volatile("s_waitcnt vmcnt(6)" ::: "memory");
      else                  asm volatile("s_waitcnt vmcnt(4)" ::: "memory");
    } else {
      asm volatile("s_waitcnt vmcnt(0)" ::: "memory");
    }
    barrier_raw();
    cb = cb + 1; if (cb >= 3) cb -= 3;
    sb = sb + 1; if (sb >= 3) sb -= 3;
  }

  // epilogue: C/D layout col = l16, row = quad*4 + reg
  if (MODE == 0) {
#pragma unroll
    for (int mf = 0; mf < MR; ++mf) {
      int row0 = m0 + wrow + mf * 16 + quad * 4;
      int b = row0 >> 11, n = row0 & 2047;
#pragma unroll
      for (int nf = 0; nf < NR; ++nf) {
        int col = n0 + wcol + nf * 16 + l16;
        float bv = bias[col];
        float v0 = acc[mf][nf][0] + bv, v1 = acc[mf][nf][1] + bv;
        float v2 = acc[mf][nf][2] + bv, v3 = acc[mf][nf][3] + bv;
        int which = col >> 10;
        int h = (col >> 6) & 15;
        int d = col & 63;
        size_t bh = (size_t)(b * 16 + h);
        if (which == 0) {             // Q, pre-scaled by SCALE*log2(e)
          const float qs = 0.18033688f;   // 0.125 * 1.44269504
          size_t base = (bh * 2048 + n) * 64 + d;
          qb[base]       = f2bf(v0 * qs);
          qb[base + 64]  = f2bf(v1 * qs);
          qb[base + 128] = f2bf(v2 * qs);
          qb[base + 192] = f2bf(v3 * qs);
        } else if (which == 1) {      // K
          size_t base = (bh * 2048 + n) * 64 + d;
          kb[base]       = f2bf(v0);
          kb[base + 64]  = f2bf(v1);
          kb[base + 128] = f2bf(v2);
          kb[base + 192] = f2bf(v3);
        } else {                      // V transposed: [bh, d, n] f16, 4 tokens
          uint2 pk;
          pk.x = pkh(v0, v1);
          pk.y = pkh(v2, v3);
          *(uint2*)&vtb[(bh * 64 + d) * 2048 + n] = pk;
        }
      }
    }
  } else {
#pragma unroll
    for (int mf = 0; mf < MR; ++mf) {
      int row0 = m0 + wrow + mf * 16 + quad * 4;
#pragma unroll
      for (int nf = 0; nf < NR; ++nf) {
        int col = n0 + wcol + nf * 16 + l16;
        float bv = bias[col];
        outp[(size_t)row0 * Nn + col]       = acc[mf][nf][0] + bv;
        outp[(size_t)(row0 + 1) * Nn + col] = acc[mf][nf][1] + bv;
        outp[(size_t)(row0 + 2) * Nn + col] = acc[mf][nf][2] + bv;
        outp[(size_t)(row0 + 3) * Nn + col] = acc[mf][nf][3] + bv;
      }
    }
  }
}

// ----------------------------- attention -----------------------------------
// One block = one (b,h) x 128 q-rows; 4 waves, 32 q-rows each. BKV = 64.
// Q pre-scaled by SCALE*log2e. qb/kb: [BH,2048,64] bf16; vtb: [BH,64,2048] f16.
// S^T = K Q^T via 16x16x32 bf16 (A=K m=kv, B=Q n=q): lane holds
// q=qt*16+l16, kv=(2*blk+vv)*16 + quad*4 + r.
// PV uses 16x16x32 f16 (A=P m=q k=kv 32-wide, B=V n=d): A-frag needs
// k=quad*8+j. R4-verified quad-exchange of packed f16 pairs:
// dst(quad t, word w) <- src(quad 2(t&1)+(w>>1), word w&1, kvt parity t>>1)
// = 8 ds_bpermute (2 const addrs) + 4 cndmask per frag.
// R8 schedule per tile (two 32-kv halves A=blk0, B=blk1):
//   QK^T(A); QK^T(B); [Vread+exp2+pack+exchange](A) overlaps QK^T(B) pipe;
//   PV(A) K=32 [setprio 1]; [Vread+exp2+pack+exchange](B) overlaps PV(A);
//   PV(B) K=32 [setprio 1].
// Denominator: lacc[qt] = mfma32(pf, ones8) — lane holds denom for exactly
// the rows it writes (C row = quad*4+r); no cross-lane reduce.
// K+V double-buffered, barrier-first prefetch, 1 barrier/tile, 4 blocks/CU.
// Bijective XCD swizzle: XCD c covers bh in [8c,8c+8) -> K/V set 4MB = L2.
// ob: [B, 2048, 1024] bf16 attention output.

__global__ __launch_bounds__(256, 4) void attn_kernel(
    const short* __restrict__ qb, const short* __restrict__ kb,
    const short* __restrict__ vtb, short* __restrict__ ob) {
  __shared__ __align__(16) short Ks[2][64 * 64];  // bf16 [kv][d]
  __shared__ __align__(16) short Vs[2][64 * 64];  // f16  [d][kv]
  const int tid = threadIdx.x, wave = tid >> 6, lane = tid & 63;
  const int quad = lane >> 4, l16 = lane & 15;
  // XCD-bijective remap: linear id n -> n' = (n%8)*128 + n/8, so XCD c
  // (blocks n with n%8==c under round-robin dispatch) covers bh in [8c,8c+8).
  int nlin = blockIdx.x + blockIdx.y * 16;
  nlin = (nlin & 7) * 128 + (nlin >> 3);
  const int q0 = (nlin & 15) * 128;
  const int bh = nlin >> 4;
  const short* Qg = qb + (size_t)bh * (2048 * 64);
  const short* Kg = kb + (size_t)bh * (2048 * 64);
  const short* Vg = vtb + (size_t)bh * (64 * 2048);

  // Q fragments: global -> registers once; B-operand layout (n=q on l16,
  // k = kc*32 + quad*8 + j contiguous d)
  short8 qf[2][2];
#pragma unroll
  for (int qt = 0; qt < 2; ++qt)
#pragma unroll
    for (int kc = 0; kc < 2; ++kc)
      qf[qt][kc] = *(const short8*)
          &Qg[(size_t)(q0 + wave * 32 + qt * 16 + l16) * 64 + kc * 32 + quad * 8];

  const int str = lane >> 3;
  const int sgc = ((lane & 7) ^ (str & 7)) * 8;   // chunk-of-8 swizzle (shorts)
  const int fsw = l16 & 7;
  const int c0 = wave * 2, c1 = wave * 2 + 1;

  // quad-exchange constants (R4-verified): src lane byte-addr for frag words.
  // addrA (words 0,1): src quad 2*(quad&1); addrB (words 2,3): +1.
  const int adA = ((lane & 16) ? 128 : 0) + l16 * 4;
  const int adB = adA + 64;
  const bool hiq = (lane & 32) != 0;              // dst quads 2,3 -> kvt odd

  // prologue: stage K/V tile 0 into buffer 0
  async16(Kg + (size_t)(c0 * 8 + str) * 64 + sgc, (char*)Ks[0] + c0 * 1024);
  async16(Kg + (size_t)(c1 * 8 + str) * 64 + sgc, (char*)Ks[0] + c1 * 1024);
  async16(Vg + (size_t)(c0 * 8 + str) * 2048 + sgc, (char*)Vs[0] + c0 * 1024);
  async16(Vg + (size_t)(c1 * 8 + str) * 2048 + sgc, (char*)Vs[0] + c1 * 1024);

  const half8 vone8 = {(_Float16)1.f, (_Float16)1.f, (_Float16)1.f, (_Float16)1.f,
                       (_Float16)1.f, (_Float16)1.f, (_Float16)1.f, (_Float16)1.f};
  const f32x4 fz = {};                           // hoisted zero C-operand
  f32x4 oacc[2][4] = {};   // [qt][nt]; C/D: col(n=d)=l16, row(m=q)=quad*4+r
  f32x4 lacc[2] = {};      // [qt]; denom for q = qt*16 + quad*4 + r

  for (int t = 0; t < 32; ++t) {
    // barrier FIRST: drains buf[t&1] loads (issued last iter / prologue,
    // overlapped with compute of t-1) and protects buffer reuse.
    __syncthreads();

    int kvn = (t + 1) * 64;
    if (kvn < 2048) {
      char* kd = (char*)Ks[(t + 1) & 1];
      char* vd = (char*)Vs[(t + 1) & 1];
      async16(Kg + (size_t)(kvn + c0 * 8 + str) * 64 + sgc, kd + c0 * 1024);
      async16(Kg + (size_t)(kvn + c1 * 8 + str) * 64 + sgc, kd + c1 * 1024);
      async16(Vg + (size_t)(c0 * 8 + str) * 2048 + kvn + sgc, vd + c0 * 1024);
      async16(Vg + (size_t)(c1 * 8 + str) * 2048 + kvn + sgc, vd + c1 * 1024);
    }
    const short* Kst = Ks[t & 1];
    const short* Vst = Vs[t & 1];

    // ---- QK^T half A (kvt 0,1) then half B (kvt 2,3): MFMA pipe fills ----
    f32x4 sA[2][2], sB[2][2];    // [qt][vv]
#pragma unroll
    for (int kc = 0; kc < 2; ++kc) {
      short8 k0 = *(const short8*)
          &Kst[(0 * 16 + l16) * 64 + (((kc * 4 + quad) ^ fsw) << 3)];
      short8 k1 = *(const short8*)
          &Kst[(1 * 16 + l16) * 64 + (((kc * 4 + quad) ^ fsw) << 3)];
#pragma unroll
      for (int qt = 0; qt < 2; ++qt) {
        sA[qt][0] = __builtin_amdgcn_mfma_f32_16x16x32_bf16(
            k0, qf[qt][kc], kc == 0 ? fz : sA[qt][0], 0, 0, 0);
        sA[qt][1] = __builtin_amdgcn_mfma_f32_16x16x32_bf16(
            k1, qf[qt][kc], kc == 0 ? fz : sA[qt][1], 0, 0, 0);
      }
    }
#pragma unroll
    for (int kc = 0; kc < 2; ++kc) {
      short8 k2 = *(const short8*)
          &Kst[(2 * 16 + l16) * 64 + (((kc * 4 + quad) ^ fsw) << 3)];
      short8 k3 = *(const short8*)
          &Kst[(3 * 16 + l16) * 64 + (((kc * 4 + quad) ^ fsw) << 3)];
#pragma unroll
      for (int qt = 0; qt < 2; ++qt) {
        sB[qt][0] = __builtin_amdgcn_mfma_f32_16x16x32_bf16(
            k2, qf[qt][kc], kc == 0 ? fz : sB[qt][0], 0, 0, 0);
        sB[qt][1] = __builtin_amdgcn_mfma_f32_16x16x32_bf16(
            k3, qf[qt][kc], kc == 0 ? fz : sB[qt][1], 0, 0, 0);
      }
    }

    // ---- half A: V b128 reads, exp2/pack, quad-exchange (overlap QK^T(B)) --
    half8 vfA[4];
#pragma unroll
    for (int nt = 0; nt < 4; ++nt)
      vfA[nt] = *(const half8*)
          &Vst[(nt * 16 + l16) * 64 + (((0 * 4 + quad) ^ fsw) << 3)];
    half8 pfA[2];
#pragma unroll
    for (int qt = 0; qt < 2; ++qt) {
      unsigned pk[2][2];           // [vv][word]
#pragma unroll
      for (int vv = 0; vv < 2; ++vv) {
        float p0 = EXP2F(sA[qt][vv][0]);
        float p1 = EXP2F(sA[qt][vv][1]);
        float p2 = EXP2F(sA[qt][vv][2]);
        float p3 = EXP2F(sA[qt][vv][3]);
        pk[vv][0] = pkh(p0, p1);
        pk[vv][1] = pkh(p2, p3);
      }
      int e0 = __builtin_amdgcn_ds_bpermute(adA, (int)pk[0][0]);
      int o0 = __builtin_amdgcn_ds_bpermute(adA, (int)pk[1][0]);
      int e1 = __builtin_amdgcn_ds_bpermute(adA, (int)pk[0][1]);
      int o1 = __builtin_amdgcn_ds_bpermute(adA, (int)pk[1][1]);
      int e2 = __builtin_amdgcn_ds_bpermute(adB, (int)pk[0][0]);
      int o2 = __builtin_amdgcn_ds_bpermute(adB, (int)pk[1][0]);
      int e3 = __builtin_amdgcn_ds_bpermute(adB, (int)pk[0][1]);
      int o3 = __builtin_amdgcn_ds_bpermute(adB, (int)pk[1][1]);
      uint4 wv;
      wv.x = (unsigned)(hiq ? o0 : e0);
      wv.y = (unsigned)(hiq ? o1 : e1);
      wv.z = (unsigned)(hiq ? o2 : e2);
      wv.w = (unsigned)(hiq ? o3 : e3);
      pfA[qt] = __builtin_bit_cast(half8, wv);
    }

    // ---- PV(A) K=32 + ones denom ----
    __builtin_amdgcn_s_setprio(1);
#pragma unroll
    for (int qt = 0; qt < 2; ++qt)
      lacc[qt] = __builtin_amdgcn_mfma_f32_16x16x32_f16(
          pfA[qt], vone8, lacc[qt], 0, 0, 0);
#pragma unroll
    for (int nt = 0; nt < 4; ++nt)
#pragma unroll
      for (int qt = 0; qt < 2; ++qt)
        oacc[qt][nt] = __builtin_amdgcn_mfma_f32_16x16x32_f16(
            pfA[qt], vfA[nt], oacc[qt][nt], 0, 0, 0);
    __builtin_amdgcn_s_setprio(0);

    // ---- half B: V b128 reads, exp2/pack, quad-exchange (overlap PV(A)) ---
    half8 vfB[4];
#pragma unroll
    for (int nt = 0; nt < 4; ++nt)
      vfB[nt] = *(const half8*)
          &Vst[(nt * 16 + l16) * 64 + (((1 * 4 + quad) ^ fsw) << 3)];
    half8 pfB[2];
#pragma unroll
    for (int qt = 0; qt < 2; ++qt) {
      unsigned pk[2][2];
#pragma unroll
      for (int vv = 0; vv < 2; ++vv) {
        float p0 = EXP2F(sB[qt][vv][0]);
        float p1 = EXP2F(sB[qt][vv][1]);
        float p2 = EXP2F(sB[qt][vv][2]);
        float p3 = EXP2F(sB[qt][vv][3]);
        pk[vv][0] = pkh(p0, p1);
        pk[vv][1] = pkh(p2, p3);
      }
      int e0 = __builtin_amdgcn_ds_bpermute(adA, (int)pk[0][0]);
      int o0 = __builtin_amdgcn_ds_bpermute(adA, (int)pk[1][0]);
      int e1 = __builtin_amdgcn_ds_bpermute(adA, (int)pk[0][1]);
      int o1 = __builtin_amdgcn_ds_bpermute(adA, (int)pk[1][1]);
      int e2 = __builtin_amdgcn_ds_bpermute(adB, (int)pk[0][0]);
      int o2 = __builtin_amdgcn_ds_bpermute(adB, (int)pk[1][0]);
      int e3 = __builtin_amdgcn_ds_bpermute(adB, (int)pk[0][1]);
      int o3 = __builtin_amdgcn_ds_bpermute(adB, (int)pk[1][1]);
      uint4 wv;
      wv.x = (unsigned)(hiq ? o0 : e0);
      wv.y = (unsigned)(hiq ? o1 : e1);
      wv.z = (unsigned)(hiq ? o2 : e2);
      wv.w = (unsigned)(hiq ? o3 : e3);
      pfB[qt] = __builtin_bit_cast(half8, wv);
    }

    // ---- PV(B) K=32 + ones denom ----
    __builtin_amdgcn_s_setprio(1);
#pragma unroll
    for (int qt = 0; qt < 2; ++qt)
      lacc[qt] = __builtin_amdgcn_mfma_f32_16x16x32_f16(
          pfB[qt], vone8, lacc[qt], 0, 0, 0);
#pragma unroll
    for (int nt = 0; nt < 4; ++nt)
#pragma unroll
      for (int qt = 0; qt < 2; ++qt)
        oacc[qt][nt] = __builtin_amdgcn_mfma_f32_16x16x32_f16(
            pfB[qt], vfB[nt], oacc[qt][nt], 0, 0, 0);
    __builtin_amdgcn_s_setprio(0);
    // no trailing barrier: next iteration's leading barrier covers reuse.
  }

  // epilogue: lane holds denom lacc[qt][r] for row q = qt*16+quad*4+r —
  // exactly the rows it writes. No cross-lane reduction needed.
  const int b = bh >> 4, h = bh & 15;
#pragma unroll
  for (int qt = 0; qt < 2; ++qt) {
    float inv0 = 1.f / lacc[qt][0], inv1 = 1.f / lacc[qt][1];
    float inv2 = 1.f / lacc[qt][2], inv3 = 1.f / lacc[qt][3];
#pragma unroll
    for (int nt = 0; nt < 4; ++nt) {
      int d = nt * 16 + l16;
      int qbase = q0 + wave * 32 + qt * 16 + quad * 4;
      size_t obase = ((size_t)(b * 2048 + qbase)) * 1024 + h * 64 + d;
      ob[obase]        = f2bf(oacc[qt][nt][0] * inv0);
      ob[obase + 1024] = f2bf(oacc[qt][nt][1] * inv1);
      ob[obase + 2048] = f2bf(oacc[qt][nt][2] * inv2);
      ob[obase + 3072] = f2bf(oacc[qt][nt][3] * inv3);
    }
  }
}

// ----------------------------- launch --------------------------------------

extern "C" void kernel_launch(void* const* d_in, const int* in_sizes, int n_in,
                              void* d_out, int out_size, void* d_ws, size_t ws_size,
                              hipStream_t stream) {
  const float* x      = (const float*)d_in[0];
  const float* w_qkv  = (const float*)d_in[1];
  const float* b_qkv  = (const float*)d_in[2];
  const float* w_proj = (const float*)d_in[3];
  const float* b_proj = (const float*)d_in[4];
  float* out = (float*)d_out;

  short* xs     = (short*)d_ws;                     // [8192,1024]
  short* wqkvT  = xs + (size_t)8192 * 1024;         // [3072,1024]
  short* wprojT = wqkvT + (size_t)3072 * 1024;      // [1024,1024]
  short* qb     = wprojT + (size_t)1024 * 1024;     // [64,2048,64]
  short* kb     = qb + (size_t)64 * 2048 * 64;      // [64,2048,64]
  short* vtb    = kb + (size_t)64 * 2048 * 64;      // [64,64,2048] f16
  short* aob    = vtb + (size_t)64 * 2048 * 64;     // [8192,1024]

  prep_kernel<<<dim3(8192), 256, 0, stream>>>(x, w_qkv, w_proj,
                                              xs, wqkvT, wprojT);

  gemm_kernel<256, 128, 0><<<dim3(24, 32), 256, 0, stream>>>(
      xs, wqkvT, b_qkv, 3072, qb, kb, vtb, nullptr);
  attn_kernel<<<dim3(16, 64), 256, 0, stream>>>(qb, kb, vtb, aob);
  gemm_kernel<128, 128, 1><<<dim3(8, 64), 256, 0, stream>>>(
      aob, wprojT, b_proj, 1024, nullptr, nullptr, nullptr, out);
}

// Round 9
// 268.942 us; speedup vs baseline: 1.0443x; 1.0443x over previous
//
#include <hip/hip_runtime.h>
#include <cstdint>
#include <cstddef>

// ---------------------------------------------------------------------------
// MSA: out = proj(softmax(Q K^T * scale) V) for B=4, N=2048, C=1024, H=16, HD=64
// bf16/f16 MFMA pipeline:
//   1. prep (ONE dispatch): x -> bf16; transpose-convert w_qkv, w_proj.
//   2. GEMM qkv: 256x128 tile, 4 waves x (128x64 out), BK=32, triple-buffered
//      LDS (2 blocks/CU), one raw barrier/K-tile, counted vmcnt.
//      XCD/L2-aware block remap.
//   3. attention (R9): 128 q/block, 4 waves x 32 q-rows, BKV=64, 32x32x16
//      MFMA shape throughout. S^T = K Q^T via mfma_f32_32x32x16_bf16
//      (A=K m=kv, B=Q n=q=lane&31): 8 MFMA/tile (was 16 16x16). P^T per lane
//      (col=q own, row=kv over regs) -> exp2 -> cvt_pkrtz -> permlane32_swap
//      (VALU! not DS - R4/R8's ds_bpermute refuted) builds the K=16 B-frags
//      -> PV via mfma_f32_32x32x16_f16 (A=V^T b128 from Vs): 8 MFMA/tile
//      (was 40 K=16 f16). Denominator: per-lane scalar adds (P^T rows are
//      all own-q) + one shfl_xor(32) at end. Issue-sum/tile ~1650 -> ~1100.
//      K+V LDS double-buffered, 1 barrier/tile, 4 blocks/CU, bijective XCD
//      swizzle (FETCH 142->28 MB measured).
//   4. GEMM proj: same kernel, 128x128 tile -> fp32 d_out
// ---------------------------------------------------------------------------

typedef __attribute__((ext_vector_type(8))) short short8;   // 8 x bf16 (4 VGPRs)
typedef __attribute__((ext_vector_type(4))) float f32x4;    // 16x16 MFMA C/D
typedef __attribute__((ext_vector_type(16))) float f32x16;  // 32x32 MFMA C/D
typedef _Float16 half8 __attribute__((ext_vector_type(8))); // 32x32x16 A/B frag
typedef __attribute__((ext_vector_type(2))) int iv2;

#if __has_builtin(__builtin_amdgcn_exp2f)
#define EXP2F(x) __builtin_amdgcn_exp2f(x)
#else
#define EXP2F(x) __expf((x) * 0.69314718056f)
#endif

__device__ __forceinline__ short f2bf(float x) {            // RNE float->bf16 bits
  unsigned u = __builtin_bit_cast(unsigned, x);
  u += 0x7fffu + ((u >> 16) & 1u);
  return (short)(u >> 16);
}

__device__ __forceinline__ unsigned pkh(float a, float b) { // pack 2xf32 -> f16x2
  auto h = __builtin_amdgcn_cvt_pkrtz(a, b);                // __fp16 ext_vector(2)
  return __builtin_bit_cast(unsigned, h);
}

__device__ __forceinline__ void async16(const void* g, void* l) {
  // 16B per lane, LDS dest = wave-uniform base + lane*16
  __builtin_amdgcn_global_load_lds(
      (const __attribute__((address_space(1))) unsigned*)g,
      (__attribute__((address_space(3))) unsigned*)l, 16, 0, 0);
}

__device__ __forceinline__ void barrier_raw() {
  __asm__ volatile("" ::: "memory");
  __builtin_amdgcn_s_barrier();
  __asm__ volatile("" ::: "memory");
}

// ------------------------------- prep --------------------------------------
// One dispatch: blocks [0,4096) convert x; [4096,7168) transpose w_qkv;
// [7168,8192) transpose w_proj. Branch is block-uniform; barriers legal.

__global__ __launch_bounds__(256) void prep_kernel(
    const float* __restrict__ x, const float* __restrict__ w_qkv,
    const float* __restrict__ w_proj, short* __restrict__ xs,
    short* __restrict__ wqkvT, short* __restrict__ wprojT) {
  __shared__ float tile[32][33];
  const int bid = blockIdx.x, tid = threadIdx.x;
  if (bid < 4096) {                                // x -> bf16, 8 elems/thread
    int i = bid * 256 + tid;
    const float4* p = (const float4*)x + (size_t)i * 2;
    float4 a = p[0], b = p[1];
    short8 r;
    r[0] = f2bf(a.x); r[1] = f2bf(a.y); r[2] = f2bf(a.z); r[3] = f2bf(a.w);
    r[4] = f2bf(b.x); r[5] = f2bf(b.y); r[6] = f2bf(b.z); r[7] = f2bf(b.w);
    *((short8*)xs + i) = r;
    return;
  }
  const float* in;
  short* out;
  int N, bx, by;
  if (bid < 4096 + 3072) {
    int b = bid - 4096;
    in = w_qkv; out = wqkvT; N = 3072; bx = b % 96; by = b / 96;
  } else {
    int b = bid - 7168;
    in = w_proj; out = wprojT; N = 1024; bx = b & 31; by = b >> 5;
  }
  const int K = 1024;
  int n0 = bx * 32, k0 = by * 32;
  int tx = tid & 31, ty = tid >> 5;                // (32,8)
  for (int r = ty; r < 32; r += 8)
    tile[r][tx] = in[(size_t)(k0 + r) * N + n0 + tx];
  __syncthreads();
  for (int r = ty; r < 32; r += 8)
    out[(size_t)(n0 + r) * K + k0 + tx] = f2bf(tile[tx][r]);
}

// ------------------------------- GEMM --------------------------------------
// C[M,Nn] = A[M,1024] * Bt[Nn,1024]^T ; BM x BN block tile, BK=32, 4 waves
// as 2Mx2N, each wave (BM/2)x(BN/2) out = (BM/32)x(BN/32) 16x16x32 MFMA/tile.
// LDS: one [BM+BN][32]-short tile per buffer, chunk-of-4 (16B) XOR swizzle
// applied at stage-source AND frag-read -> conflict-free b128 reads.
// TRIPLE buffered: while computing tile t, stage t+2; end-of-tile wait
// vmcnt(L) keeps t+2's L loads in flight. ONE raw s_barrier per K-tile.
// Block remap: XCD c (id%8) owns m-panels [c*MC,(c+1)*MC); n in chunks of 8.
// MODE 0: QKV epilogue (bias, scale Q by SCALE*log2e, scatter q/k bf16, vT f16)
// MODE 1: proj epilogue (bias, fp32 out)

template <int BM, int BN, int MODE>
__global__ __launch_bounds__(256, 2) void gemm_kernel(
    const short* __restrict__ A, const short* __restrict__ Bt,
    const float* __restrict__ bias, int Nn,
    short* __restrict__ qb, short* __restrict__ kb, short* __restrict__ vtb,
    float* __restrict__ outp) {
  constexpr int K = 1024;
  constexpr int NT = K / 32;                       // 32 K-tiles
  constexpr int MR = BM / 32, NR = BN / 32;        // frags per wave
  constexpr int L = (BM + BN) / 64;                // async16 per thread per tile
  __shared__ __align__(16) short Ts[3][(BM + BN) * 32];
  const int tid = threadIdx.x, wave = tid >> 6, lane = tid & 63;
  const int quad = lane >> 4, l16 = lane & 15;

  // XCD/L2-aware remap: id -> (c = id%8, j = id/8); XCD c owns MC m-panels;
  // within, n in chunks of 8 (requires gridDim.x*gridDim.y % 8 == 0).
  const unsigned bid = blockIdx.x + gridDim.x * blockIdx.y;
  const unsigned c = bid & 7u, j = bid >> 3;
  const unsigned MC = gridDim.y >> 3;              // m-panels per XCD
  const unsigned chunk = MC * 8u;                  // blocks per n-chunk per XCD
  const unsigned nc = j / chunk, rem = j - nc * chunk;
  const unsigned m_idx = c * MC + (rem >> 3);
  const unsigned n_idx = nc * 8u + (rem & 7u);
  const int m0 = (int)m_idx * BM, n0 = (int)n_idx * BN;

  const int wrow = (wave >> 1) * (BM / 2), wcol = (wave & 1) * (BN / 2);

  // staging: row = i*64 + (tid>>2), 16B chunk = tid&3, src chunk XOR (row&3)
  const int srow = tid >> 2;
  const int sch8 = (((tid & 3) ^ (srow & 3)) * 8);          // shorts
  const short* Ag = A + (size_t)(m0 + srow) * K + sch8;
  const short* Bg = Bt + (size_t)(n0 + srow) * K + sch8;
  const int fq8 = ((quad ^ (l16 & 3)) * 8);                 // frag chunk (shorts)

  f32x4 acc[MR][NR] = {};

  auto stage = [&](int b, int kt) {
    char* dst = (char*)Ts[b] + tid * 16;
#pragma unroll
    for (int i = 0; i < BM / 64; ++i)
      async16(Ag + (size_t)(i * 64) * K + kt * 32, dst + i * 4096);
#pragma unroll
    for (int i = 0; i < BN / 64; ++i)
      async16(Bg + (size_t)(i * 64) * K + kt * 32, dst + (BM / 64 + i) * 4096);
  };

  // prologue: stage tiles 0,1 into bufs 0,1; wait tile 0 (keep 1 in flight)
  stage(0, 0);
  stage(1, 1);
  if constexpr (L == 6) asm volatile("s_waitcnt vmcnt(6)" ::: "memory");
  else                  asm volatile("s_waitcnt vmcnt(4)" ::: "memory");
  barrier_raw();

  int cb = 0, sb = 2;
  for (int t = 0; t < NT; ++t) {
    if (t + 2 < NT) stage(sb, t + 2);

    const short* Tb = Ts[cb];
    short8 af[MR], bf[NR];
#pragma unroll
    for (int mf = 0; mf < MR; ++mf)
      af[mf] = *(const short8*)&Tb[(wrow + mf * 16 + l16) * 32 + fq8];
#pragma unroll
    for (int nf = 0; nf < NR; ++nf)
      bf[nf] = *(const short8*)&Tb[(BM + wcol + nf * 16 + l16) * 32 + fq8];

    __builtin_amdgcn_s_setprio(1);
#pragma unroll
    for (int mf = 0; mf < MR; ++mf)
#pragma unroll
      for (int nf = 0; nf < NR; ++nf)
        acc[mf][nf] = __builtin_amdgcn_mfma_f32_16x16x32_bf16(
            af[mf], bf[nf], acc[mf][nf], 0, 0, 0);
    __builtin_amdgcn_s_setprio(0);

    // counted wait: keep t+2's L loads in flight; t+1's (a tile old) retired.
    if (t + 2 < NT) {
      if constexpr (L == 6) asm volatile("s_waitcnt vmcnt(6)" ::: "memory");
      else                  asm volatile("s_waitcnt vmcnt(4)" ::: "memory");
    } else {
      asm volatile("s_waitcnt vmcnt(0)" ::: "memory");
    }
    barrier_raw();
    cb = cb + 1; if (cb >= 3) cb -= 3;
    sb = sb + 1; if (sb >= 3) sb -= 3;
  }

  // epilogue: C/D layout col = l16, row = quad*4 + reg
  if (MODE == 0) {
#pragma unroll
    for (int mf = 0; mf < MR; ++mf) {
      int row0 = m0 + wrow + mf * 16 + quad * 4;
      int b = row0 >> 11, n = row0 & 2047;
#pragma unroll
      for (int nf = 0; nf < NR; ++nf) {
        int col = n0 + wcol + nf * 16 + l16;
        float bv = bias[col];
        float v0 = acc[mf][nf][0] + bv, v1 = acc[mf][nf][1] + bv;
        float v2 = acc[mf][nf][2] + bv, v3 = acc[mf][nf][3] + bv;
        int which = col >> 10;
        int h = (col >> 6) & 15;
        int d = col & 63;
        size_t bh = (size_t)(b * 16 + h);
        if (which == 0) {             // Q, pre-scaled by SCALE*log2(e)
          const float qs = 0.18033688f;   // 0.125 * 1.44269504
          size_t base = (bh * 2048 + n) * 64 + d;
          qb[base]       = f2bf(v0 * qs);
          qb[base + 64]  = f2bf(v1 * qs);
          qb[base + 128] = f2bf(v2 * qs);
          qb[base + 192] = f2bf(v3 * qs);
        } else if (which == 1) {      // K
          size_t base = (bh * 2048 + n) * 64 + d;
          kb[base]       = f2bf(v0);
          kb[base + 64]  = f2bf(v1);
          kb[base + 128] = f2bf(v2);
          kb[base + 192] = f2bf(v3);
        } else {                      // V transposed: [bh, d, n] f16, 4 tokens
          uint2 pk;
          pk.x = pkh(v0, v1);
          pk.y = pkh(v2, v3);
          *(uint2*)&vtb[(bh * 64 + d) * 2048 + n] = pk;
        }
      }
    }
  } else {
#pragma unroll
    for (int mf = 0; mf < MR; ++mf) {
      int row0 = m0 + wrow + mf * 16 + quad * 4;
#pragma unroll
      for (int nf = 0; nf < NR; ++nf) {
        int col = n0 + wcol + nf * 16 + l16;
        float bv = bias[col];
        outp[(size_t)row0 * Nn + col]       = acc[mf][nf][0] + bv;
        outp[(size_t)(row0 + 1) * Nn + col] = acc[mf][nf][1] + bv;
        outp[(size_t)(row0 + 2) * Nn + col] = acc[mf][nf][2] + bv;
        outp[(size_t)(row0 + 3) * Nn + col] = acc[mf][nf][3] + bv;
      }
    }
  }
}

// ----------------------------- attention -----------------------------------
// One block = one (b,h) x 128 q-rows; 4 waves, 32 q-rows each (q = lane&31).
// BKV = 64. Q pre-scaled by SCALE*log2e. qb/kb: [BH,2048,64] bf16;
// vtb: [BH,64,2048] f16.
// QK^T: S^T[kv][q] via mfma_f32_32x32x16_bf16, A=K (m=kv=blk*32+l31,
// k=d=ds*16+hi*8+j), B=Q (n=q=l31, k same): 2 kv-blocks x 4 d-steps = 8 MFMA.
// C/D 32x32 layout: col=lane&31(=q), row=(reg&3)+8*(reg>>2)+4*hi (=kv).
// P^T: exp2 -> cvt_pkrtz pairs (words i: kv {4i..} pattern) -> B-frags for
// K=16 PV need lo-lanes kv 0-7 / hi-lanes kv 8-15 per sub-step:
// permlane32_swap(w[4s],w[4s+2]) -> frag words (w0,w2); (w[4s+1],w[4s+3]) ->
// (w1,w3). VALU op, no DS. PV: O^T[d][q] via mfma_f32_32x32x16_f16,
// A=V^T (m=d=db*32+l31, k=kv, b128 from Vs), B=P^T: 2 d-blocks x 4 kv-steps
// = 8 MFMA. Denominator: P^T rows are all own-q -> scalar adds + one
// shfl_xor(32) at end. K+V double-buffered, 1 barrier/tile, 4 blocks/CU.
// Bijective XCD swizzle: XCD c covers bh in [8c,8c+8) -> K/V set 4MB = L2.
// ob: [B, 2048, 1024] bf16 attention output.

__global__ __launch_bounds__(256, 4) void attn_kernel(
    const short* __restrict__ qb, const short* __restrict__ kb,
    const short* __restrict__ vtb, short* __restrict__ ob) {
  __shared__ __align__(16) short Ks[2][64 * 64];  // bf16 [kv][d]
  __shared__ __align__(16) short Vs[2][64 * 64];  // f16  [d][kv]
  const int tid = threadIdx.x, wave = tid >> 6, lane = tid & 63;
  const int l31 = lane & 31, hi = lane >> 5;
  // XCD-bijective remap: linear id n -> n' = (n%8)*128 + n/8, so XCD c
  // (blocks n with n%8==c under round-robin dispatch) covers bh in [8c,8c+8).
  int nlin = blockIdx.x + blockIdx.y * 16;
  nlin = (nlin & 7) * 128 + (nlin >> 3);
  const int q0 = (nlin & 15) * 128;
  const int bh = nlin >> 4;
  const short* Qg = qb + (size_t)bh * (2048 * 64);
  const short* Kg = kb + (size_t)bh * (2048 * 64);
  const short* Vg = vtb + (size_t)bh * (64 * 2048);

  const int qrow = q0 + wave * 32 + l31;
  // Q fragments: B-operand of 32x32x16 (n=q=l31, k=ds*16 + hi*8 + j)
  short8 qf[4];
#pragma unroll
  for (int ds = 0; ds < 4; ++ds)
    qf[ds] = *(const short8*)&Qg[(size_t)qrow * 64 + ds * 16 + hi * 8];

  const int str = lane >> 3;
  const int sgc = ((lane & 7) ^ (str & 7)) * 8;   // chunk-of-8 swizzle (shorts)
  const int c0 = wave * 2, c1 = wave * 2 + 1;

  // prologue: stage K/V tile 0 into buffer 0
  async16(Kg + (size_t)(c0 * 8 + str) * 64 + sgc, (char*)Ks[0] + c0 * 1024);
  async16(Kg + (size_t)(c1 * 8 + str) * 64 + sgc, (char*)Ks[0] + c1 * 1024);
  async16(Vg + (size_t)(c0 * 8 + str) * 2048 + sgc, (char*)Vs[0] + c0 * 1024);
  async16(Vg + (size_t)(c1 * 8 + str) * 2048 + sgc, (char*)Vs[0] + c1 * 1024);

  const f32x16 fz16 = {};                        // hoisted zero C-operand
  f32x16 oacc[2] = {};     // [dblk]; C/D: col=q=l31, row=d over regs
  float dsum = 0.f;        // denominator partial for q = l31 (own rows)

  for (int t = 0; t < 32; ++t) {
    // barrier FIRST: drains buf[t&1] loads (issued last iter / prologue,
    // overlapped with compute of t-1) and protects buffer reuse.
    __syncthreads();

    int kvn = (t + 1) * 64;
    if (kvn < 2048) {
      char* kd = (char*)Ks[(t + 1) & 1];
      char* vd = (char*)Vs[(t + 1) & 1];
      async16(Kg + (size_t)(kvn + c0 * 8 + str) * 64 + sgc, kd + c0 * 1024);
      async16(Kg + (size_t)(kvn + c1 * 8 + str) * 64 + sgc, kd + c1 * 1024);
      async16(Vg + (size_t)(c0 * 8 + str) * 2048 + kvn + sgc, vd + c0 * 1024);
      async16(Vg + (size_t)(c1 * 8 + str) * 2048 + kvn + sgc, vd + c1 * 1024);
    }
    const short* Kst = Ks[t & 1];
    const short* Vst = Vs[t & 1];

    // ---- QK^T: S^T[kv][q], 2 kv-blocks x 4 d-steps of 32x32x16 bf16 ----
    f32x16 sacc[2];
#pragma unroll
    for (int blk = 0; blk < 2; ++blk) {
      const int row = blk * 32 + l31;
      const int key = row & 7;
#pragma unroll
      for (int ds = 0; ds < 4; ++ds) {
        short8 kfr = *(const short8*)
            &Kst[row * 64 + (((ds * 2 + hi) ^ key) << 3)];
        sacc[blk] = __builtin_amdgcn_mfma_f32_32x32x16_bf16(
            kfr, qf[ds], ds == 0 ? fz16 : sacc[blk], 0, 0, 0);
      }
    }

    // ---- per kv-block: exp2/pack (VALU) -> permlane32_swap -> PV ----
#pragma unroll
    for (int blk = 0; blk < 2; ++blk) {
      unsigned w[8];
#pragma unroll
      for (int i = 0; i < 8; ++i) {
        float p0 = EXP2F(sacc[blk][2 * i]);
        float p1 = EXP2F(sacc[blk][2 * i + 1]);
        dsum += p0 + p1;
        w[i] = pkh(p0, p1);
      }
      half8 pf[2];
#pragma unroll
      for (int s = 0; s < 2; ++s) {
        iv2 r1 = __builtin_amdgcn_permlane32_swap(
            (int)w[4 * s + 0], (int)w[4 * s + 2], false, false);
        iv2 r2 = __builtin_amdgcn_permlane32_swap(
            (int)w[4 * s + 1], (int)w[4 * s + 3], false, false);
        uint4 u;
        u.x = (unsigned)r1[0];
        u.y = (unsigned)r2[0];
        u.z = (unsigned)r1[1];
        u.w = (unsigned)r2[1];
        pf[s] = __builtin_bit_cast(half8, u);
      }
      // PV: A=V^T (m=d, k=kv), B=P^T; kv-step = blk*2+s
      __builtin_amdgcn_s_setprio(1);
#pragma unroll
      for (int s = 0; s < 2; ++s) {
        const int kvs = blk * 2 + s;
#pragma unroll
        for (int db = 0; db < 2; ++db) {
          const int vrow = db * 32 + l31;
          half8 vf = *(const half8*)
              &Vst[vrow * 64 + (((kvs * 2 + hi) ^ (vrow & 7)) << 3)];
          oacc[db] = __builtin_amdgcn_mfma_f32_32x32x16_f16(
              vf, pf[s], oacc[db], 0, 0, 0);
        }
      }
      __builtin_amdgcn_s_setprio(0);
    }
    // no trailing barrier: next iteration's leading barrier covers reuse.
  }

  // epilogue: lanes l and l+32 share q; their d-rows and dsum halves are
  // complementary. One shfl_xor completes the denominator.
  dsum += __shfl_xor(dsum, 32, 64);
  const float inv = 1.f / dsum;
  const int b = bh >> 4, h = bh & 15;
  const size_t rowbase = ((size_t)(b * 2048 + qrow)) * 1024 + h * 64;
#pragma unroll
  for (int db = 0; db < 2; ++db)
#pragma unroll
    for (int i = 0; i < 8; ++i) {
      const int d0 = ((2 * i) & 3) + 8 * (i >> 1) + 4 * hi + 32 * db;
      unsigned s0 = (unsigned short)f2bf(oacc[db][2 * i] * inv);
      unsigned s1 = (unsigned short)f2bf(oacc[db][2 * i + 1] * inv);
      *(unsigned*)&ob[rowbase + d0] = s0 | (s1 << 16);
    }
}

// ----------------------------- launch --------------------------------------

extern "C" void kernel_launch(void* const* d_in, const int* in_sizes, int n_in,
                              void* d_out, int out_size, void* d_ws, size_t ws_size,
                              hipStream_t stream) {
  const float* x      = (const float*)d_in[0];
  const float* w_qkv  = (const float*)d_in[1];
  const float* b_qkv  = (const float*)d_in[2];
  const float* w_proj = (const float*)d_in[3];
  const float* b_proj = (const float*)d_in[4];
  float* out = (float*)d_out;

  short* xs     = (short*)d_ws;                     // [8192,1024]
  short* wqkvT  = xs + (size_t)8192 * 1024;         // [3072,1024]
  short* wprojT = wqkvT + (size_t)3072 * 1024;      // [1024,1024]
  short* qb     = wprojT + (size_t)1024 * 1024;     // [64,2048,64]
  short* kb     = qb + (size_t)64 * 2048 * 64;      // [64,2048,64]
  short* vtb    = kb + (size_t)64 * 2048 * 64;      // [64,64,2048] f16
  short* aob    = vtb + (size_t)64 * 2048 * 64;     // [8192,1024]

  prep_kernel<<<dim3(8192), 256, 0, stream>>>(x, w_qkv, w_proj,
                                              xs, wqkvT, wprojT);

  gemm_kernel<256, 128, 0><<<dim3(24, 32), 256, 0, stream>>>(
      xs, wqkvT, b_qkv, 3072, qb, kb, vtb, nullptr);
  attn_kernel<<<dim3(16, 64), 256, 0, stream>>>(qb, kb, vtb, aob);
  gemm_kernel<128, 128, 1><<<dim3(8, 64), 256, 0, stream>>>(
      aob, wprojT, b_proj, 1024, nullptr, nullptr, nullptr, out);
}